// Round 18
// baseline (1532.697 us; speedup 1.0000x reference)
//
#include <hip/hip_runtime.h>
#include <math.h>

#define T_STEPS 30
#define BATCH   64
#define HID     1024
#define VOCABN  32000
#define G3      3072
#define ROWS    (T_STEPS * BATCH)   // 1920
#define ROWS_PAD 2048
#define OUT_HID_OFF ((size_t)BATCH * T_STEPS * VOCABN)  // 61,440,000

typedef __attribute__((ext_vector_type(8))) short bf16x8;
typedef __attribute__((ext_vector_type(4))) float f32x4;

__device__ __forceinline__ unsigned short f2bf(float f) {
    union { float f; unsigned u; } x; x.f = f;
    unsigned r = x.u + 0x7fffu + ((x.u >> 16) & 1u);
    return (unsigned short)(r >> 16);
}
__device__ __forceinline__ float bf2f(unsigned short u) {
    union { unsigned u; float f; } x; x.u = (unsigned)u << 16;
    return x.f;
}

__device__ __forceinline__ void gld_lds16(const unsigned short* g, unsigned short* l) {
    __builtin_amdgcn_global_load_lds(
        (const __attribute__((address_space(1))) unsigned*)g,
        (__attribute__((address_space(3))) unsigned*)l, 16, 0, 0);
}

// ---------------------------------------------------------------- fp32 -> bf16 (RNE)
__global__ __launch_bounds__(256) void f32_to_bf16(const float* __restrict__ src,
                                                   unsigned short* __restrict__ dst, int n4) {
    int i = blockIdx.x * 256 + threadIdx.x;
    int stride = gridDim.x * 256;
    for (; i < n4; i += stride) {
        float4 v = ((const float4*)src)[i];
        ushort4 o;
        o.x = f2bf(v.x); o.y = f2bf(v.y); o.z = f2bf(v.z); o.w = f2bf(v.w);
        ((ushort4*)dst)[i] = o;
    }
}

// ---------------------------------------------------------------- X = relu(emb[tok]) -> bf16
__global__ __launch_bounds__(256) void embed_relu_bf16(const int* __restrict__ target,
                                                       const float* __restrict__ emb,
                                                       unsigned short* __restrict__ X) {
    int bid = blockIdx.x;           // t*64 + b
    int t = bid >> 6, b = bid & 63;
    int tok = (t == 0) ? 0 : target[b * T_STEPS + (t - 1)];
    const float4* src = (const float4*)(emb + (size_t)tok * HID);
    float4 v = src[threadIdx.x];
    ushort4 o;
    o.x = f2bf(fmaxf(v.x, 0.f)); o.y = f2bf(fmaxf(v.y, 0.f));
    o.z = f2bf(fmaxf(v.z, 0.f)); o.w = f2bf(fmaxf(v.w, 0.f));
    ((ushort4*)(X + (size_t)bid * HID))[threadIdx.x] = o;
}

// ---------------------------------------------------------------- barrier flags init
__global__ void init_bar(unsigned int* bar) {
    if (threadIdx.x < 64) bar[threadIdx.x] = 0u;
}

// ---------------------------------------------------------------- gi GEMM (unchanged 128^2)
__global__ __launch_bounds__(256) void gemm_mfma_bt(const unsigned short* __restrict__ A,
                                                    const unsigned short* __restrict__ W,
                                                    const float* __restrict__ bias,
                                                    float* __restrict__ out,
                                                    int N, int K) {
    __shared__ unsigned short As[128 * 64];
    __shared__ unsigned short Bs[128 * 64];
    int tid  = threadIdx.x;
    int lane = tid & 63;
    int wid  = tid >> 6;
    int wm   = wid >> 1, wn = wid & 1;
    const int bM = blockIdx.y * 128;
    const int bN = blockIdx.x * 128;

    f32x4 acc[4][4];
#pragma unroll
    for (int i = 0; i < 4; ++i)
#pragma unroll
        for (int j = 0; j < 4; ++j) acc[i][j] = (f32x4){0.f, 0.f, 0.f, 0.f};

    int sr[4], sc[4];
#pragma unroll
    for (int q = 0; q < 4; ++q) {
        sr[q] = (wid * 4 + q) * 8 + (lane >> 3);
        sc[q] = (lane & 7) ^ (sr[q] & 7);
    }

    for (int kt = 0; kt < K; kt += 64) {
        __syncthreads();
#pragma unroll
        for (int q = 0; q < 4; ++q) {
            gld_lds16(A + (size_t)(bM + sr[q]) * K + kt + sc[q] * 8, As + (wid * 4 + q) * 512);
            gld_lds16(W + (size_t)(bN + sr[q]) * K + kt + sc[q] * 8, Bs + (wid * 4 + q) * 512);
        }
        __syncthreads();

#pragma unroll
        for (int ks = 0; ks < 2; ++ks) {
            bf16x8 a[4], b[4];
#pragma unroll
            for (int mf = 0; mf < 4; ++mf) {
                int r  = wm * 64 + mf * 16 + (lane & 15);
                int ch = (ks * 4 + (lane >> 4)) ^ (r & 7);
                a[mf] = *(const bf16x8*)(As + r * 64 + ch * 8);
            }
#pragma unroll
            for (int nf = 0; nf < 4; ++nf) {
                int r  = wn * 64 + nf * 16 + (lane & 15);
                int ch = (ks * 4 + (lane >> 4)) ^ (r & 7);
                b[nf] = *(const bf16x8*)(Bs + r * 64 + ch * 8);
            }
#pragma unroll
            for (int mf = 0; mf < 4; ++mf)
#pragma unroll
                for (int nf = 0; nf < 4; ++nf)
                    acc[mf][nf] = __builtin_amdgcn_mfma_f32_16x16x32_bf16(
                        a[mf], b[nf], acc[mf][nf], 0, 0, 0);
        }
    }

    int rif = (lane >> 4) * 4;
    int col = lane & 15;
#pragma unroll
    for (int mf = 0; mf < 4; ++mf) {
#pragma unroll
        for (int j = 0; j < 4; ++j) {
            int gr = bM + wm * 64 + mf * 16 + rif + j;
#pragma unroll
            for (int nf = 0; nf < 4; ++nf) {
                int gc = bN + wn * 64 + nf * 16 + col;
                out[(size_t)gr * N + gc] = acc[mf][nf][j] + bias[gc];
            }
        }
    }
}

// ---------------------------------------------------------------- logits GEMM: 256^2 tile,
// r17 2-slot counted-vmcnt ring + XCD panel-grouping: grid 1024, block d ->
// xcd=d&7, mt=(d>>3)&7, pg=d>>6, panel p=pg*8+xcd. All 8 M-tiles of a panel
// share d%8 => one XCD's L2 fetches each 0.5 MB OutW panel exactly once;
// each XCD's 8 A-tiles (4 MB) stay L2-resident. 24 tail blocks (p>=125) idle.
template <bool BF16OUT>
__global__ __launch_bounds__(512, 4) void gemm_logits256(const unsigned short* __restrict__ A,
                                                         const unsigned short* __restrict__ W,
                                                         const float* __restrict__ bias,
                                                         float* __restrict__ out,
                                                         unsigned short* __restrict__ scratch) {
    __shared__ unsigned short As[2][256 * 32];   // 16 KB per slot
    __shared__ unsigned short Bs[2][256 * 32];
    int d   = blockIdx.x;
    int xcd = d & 7;
    int mt  = (d >> 3) & 7;
    int pg  = d >> 6;
    int p   = pg * 8 + xcd;
    if (p >= VOCABN / 256) return;     // 125 panels
    const int bM = mt * 256;
    const int bN = p * 256;

    int tid  = threadIdx.x;
    int lane = tid & 63;
    int wid  = tid >> 6;         // 0..7
    int wm   = wid >> 2;         // 0..1 -> 128 M-rows
    int wn   = wid & 3;          // 0..3 -> 64 N-cols
    int l15  = lane & 15, l4 = lane >> 4;

    size_t pA[2], pB[2];
    int ldst[2];
#pragma unroll
    for (int i = 0; i < 2; ++i) {
        int c = wid * 128 + i * 64 + lane;
        int r = c >> 2, cc = c & 3;
        int so = (cc ^ ((r >> 1) & 3)) * 8;
        pA[i] = (size_t)(bM + r) * HID + so;
        pB[i] = (size_t)(bN + r) * HID + so;
        ldst[i] = wid * 1024 + i * 512;
    }

    f32x4 acc[8][4];
#pragma unroll
    for (int i = 0; i < 8; ++i)
#pragma unroll
        for (int j = 0; j < 4; ++j) acc[i][j] = (f32x4){0.f, 0.f, 0.f, 0.f};

    int chsw = (l4 ^ ((l15 >> 1) & 3)) * 8;
    int aoff[8], boff[4];
#pragma unroll
    for (int mf = 0; mf < 8; ++mf) aoff[mf] = (wm * 128 + mf * 16 + l15) * 32 + chsw;
#pragma unroll
    for (int nf = 0; nf < 4; ++nf) boff[nf] = (wn * 64 + nf * 16 + l15) * 32 + chsw;

    auto issue = [&](int s) {
        int slot = s & 1;
#pragma unroll
        for (int i = 0; i < 2; ++i)
            gld_lds16(A + pA[i] + s * 32, &As[slot][ldst[i]]);
#pragma unroll
        for (int i = 0; i < 2; ++i)
            gld_lds16(W + pB[i] + s * 32, &Bs[slot][ldst[i]]);
    };

    issue(0); issue(1);          // 8 vmem instrs in flight per wave

#pragma unroll 1
    for (int s = 0; s < 32; ++s) {
        if (s < 31) asm volatile("s_waitcnt vmcnt(4)" ::: "memory");   // sub-tile s landed
        else        asm volatile("s_waitcnt vmcnt(0)" ::: "memory");
        __builtin_amdgcn_s_barrier();      // all waves: s landed
        asm volatile("" ::: "memory");
        __builtin_amdgcn_sched_barrier(0);

        int slot = s & 1;
        const unsigned short* ab = As[slot];
        const unsigned short* bb = Bs[slot];
        bf16x8 a[8], b[4];
#pragma unroll
        for (int mf = 0; mf < 8; ++mf) a[mf] = *(const bf16x8*)(ab + aoff[mf]);
#pragma unroll
        for (int nf = 0; nf < 4; ++nf) b[nf] = *(const bf16x8*)(bb + boff[nf]);
        __builtin_amdgcn_s_setprio(1);
#pragma unroll
        for (int mf = 0; mf < 8; ++mf)
#pragma unroll
            for (int nf = 0; nf < 4; ++nf)
                acc[mf][nf] = __builtin_amdgcn_mfma_f32_16x16x32_bf16(
                    a[mf], b[nf], acc[mf][nf], 0, 0, 0);
        __builtin_amdgcn_s_setprio(0);

        asm volatile("s_waitcnt lgkmcnt(0)" ::: "memory");  // this wave's slot reads done
        __builtin_amdgcn_s_barrier();      // all waves done reading slot s&1
        asm volatile("" ::: "memory");
        __builtin_amdgcn_sched_barrier(0);
        if (s < 30) issue(s + 2);          // overwrite slot s&1, lands by iter s+2
    }

    int col = l15;
    float b4[4];
#pragma unroll
    for (int nf = 0; nf < 4; ++nf) b4[nf] = bias[bN + wn * 64 + nf * 16 + col];
    int rif = l4 * 4;
#pragma unroll
    for (int mf = 0; mf < 8; ++mf) {
#pragma unroll
        for (int j = 0; j < 4; ++j) {
            int gr = bM + wm * 128 + mf * 16 + rif + j;
            if (gr < ROWS) {
                int t = gr >> 6, b_ = gr & 63;
                size_t rowoff = ((size_t)b_ * T_STEPS + t) * (size_t)VOCABN;
#pragma unroll
                for (int nf = 0; nf < 4; ++nf) {
                    float v = acc[mf][nf][j] + b4[nf];
                    int gc = bN + wn * 64 + nf * 16 + col;
                    if (BF16OUT) scratch[rowoff + gc] = f2bf(v);
                    else         out[rowoff + gc] = v;
                }
            }
        }
    }
}

// ---------------------------------------------------------------- persistent 30-step GRU
// (r15: blocks 0-63 recurrence; 64-255 OutW convert hidden under recurrence)
__global__ __launch_bounds__(256, 1) void gru_persistent(
    const unsigned short* __restrict__ h0b,
    const float* __restrict__ enc_h,
    const unsigned short* __restrict__ Whh,
    const float* __restrict__ b_hh,
    const float* __restrict__ gi,
    unsigned short* __restrict__ Hall,
    float* __restrict__ h_final,
    unsigned int* __restrict__ flags,
    const float* __restrict__ outw_f32,
    unsigned short* __restrict__ outw_bf)
{
    __shared__ unsigned short Wlds[48 * 1024];   // 96 KB
    int tid  = threadIdx.x;

    if (blockIdx.x >= 64) {
        const int n4 = VOCABN * HID / 4;
        int i = (blockIdx.x - 64) * 256 + tid;
        const int stride = 192 * 256;
        for (; i < n4; i += stride) {
            float4 v = ((const float4*)outw_f32)[i];
            ushort4 o;
            o.x = f2bf(v.x); o.y = f2bf(v.y); o.z = f2bf(v.z); o.w = f2bf(v.w);
            ((ushort4*)outw_bf)[i] = o;
        }
        return;
    }

    int lane = tid & 63;
    int wq   = tid >> 6;
    int l15  = lane & 15, l4 = lane >> 4;
    int m0   = blockIdx.x * 16;
    int b    = wq * 16 + l15;
    int mb   = m0 + l4 * 4;

    for (int i = 0; i < 24; ++i) {
        int sb = wq * 24 + i;
        int kt = sb / 3, g = sb % 3;
        const unsigned short* src =
            Whh + (size_t)(g * HID + m0 + l15) * HID + kt * 32 + l4 * 8;
        gld_lds16(src, Wlds + sb * 512);
    }

    float hp[4];
    {
        float4 h4 = *(const float4*)(enc_h + (size_t)b * HID + mb);
        hp[0] = h4.x; hp[1] = h4.y; hp[2] = h4.z; hp[3] = h4.w;
    }
    float bhr[4], bhz[4], bhn[4];
    {
        float4 r4 = *(const float4*)(b_hh + mb);
        float4 z4 = *(const float4*)(b_hh + HID + mb);
        float4 n4 = *(const float4*)(b_hh + 2 * HID + mb);
        bhr[0]=r4.x; bhr[1]=r4.y; bhr[2]=r4.z; bhr[3]=r4.w;
        bhz[0]=z4.x; bhz[1]=z4.y; bhz[2]=z4.z; bhz[3]=z4.w;
        bhn[0]=n4.x; bhn[1]=n4.y; bhn[2]=n4.z; bhn[3]=n4.w;
    }
    __syncthreads();

    int arow16 = b * 128 + l4;

    for (int t = 0; t < T_STEPS; ++t) {
        const float* gib = gi + (size_t)t * BATCH * G3 + (size_t)b * G3;
        float4 giR = *(const float4*)(gib + mb);
        float4 giZ = *(const float4*)(gib + HID + mb);
        float4 giN = *(const float4*)(gib + 2 * HID + mb);
        float gr4[4] = {giR.x, giR.y, giR.z, giR.w};
        float gz4[4] = {giZ.x, giZ.y, giZ.z, giZ.w};
        float gn4[4] = {giN.x, giN.y, giN.z, giN.w};

        if (t > 0) {
            if (tid < 64) {
                while (__hip_atomic_load(flags + tid, __ATOMIC_RELAXED,
                                         __HIP_MEMORY_SCOPE_AGENT) < (unsigned)t) {}
            }
            __builtin_amdgcn_sched_barrier(0);
            __syncthreads();
            asm volatile("" ::: "memory");
        }

        const unsigned short* Asrc = (t == 0) ? h0b : (Hall + (size_t)(t - 1) * BATCH * HID);
        const bf16x8* A16 = (const bf16x8*)Asrc;

        bf16x8 hreg[32];
#pragma unroll
        for (int kt = 0; kt < 32; ++kt) hreg[kt] = A16[arow16 + kt * 4];

        f32x4 acc[3];
#pragma unroll
        for (int g = 0; g < 3; ++g) acc[g] = (f32x4){0.f, 0.f, 0.f, 0.f};

#pragma unroll
        for (int kt = 0; kt < 32; ++kt) {
#pragma unroll
            for (int g = 0; g < 3; ++g) {
                bf16x8 wfrag = *(const bf16x8*)(Wlds + ((size_t)(kt * 3 + g) * 64 + lane) * 8);
                acc[g] = __builtin_amdgcn_mfma_f32_16x16x32_bf16(wfrag, hreg[kt], acc[g], 0, 0, 0);
            }
        }

        unsigned long long pack = 0;
#pragma unroll
        for (int j = 0; j < 4; ++j) {
            float r = 1.f / (1.f + __expf(-(gr4[j] + acc[0][j] + bhr[j])));
            float z = 1.f / (1.f + __expf(-(gz4[j] + acc[1][j] + bhz[j])));
            float e2 = __expf(2.f * (gn4[j] + r * (acc[2][j] + bhn[j])));
            float n = 1.f - 2.f / (e2 + 1.f);   // tanh
            float hnew = (1.f - z) * n + z * hp[j];
            hp[j] = hnew;
            pack |= (unsigned long long)f2bf(hnew) << (16 * j);
        }
        __hip_atomic_store((unsigned long long*)(Hall + (size_t)t * BATCH * HID +
                                                 (size_t)b * HID + mb),
                           pack, __ATOMIC_RELAXED, __HIP_MEMORY_SCOPE_AGENT);
        if (t == T_STEPS - 1) {
            float4 hf = {hp[0], hp[1], hp[2], hp[3]};
            *(float4*)(h_final + (size_t)b * HID + mb) = hf;
        }

        if (t < T_STEPS - 1) {
            __syncthreads();
            if (tid == 0)
                __hip_atomic_store(flags + blockIdx.x, (unsigned)(t + 1),
                                   __ATOMIC_RELAXED, __HIP_MEMORY_SCOPE_AGENT);
        }
    }
}

// ---------------------------------------------------------------- fused log-softmax from bf16
__global__ __launch_bounds__(256) void lsm_fused_bf16(const unsigned short* __restrict__ scratch,
                                                      float* __restrict__ out) {
    __shared__ bf16x8 srow[4000];    // 64 KB
    __shared__ float2 sred[4];
    __shared__ float sc;
    const bf16x8* src = (const bf16x8*)(scratch + (size_t)blockIdx.x * VOCABN);
    float* dst = out + (size_t)blockIdx.x * VOCABN;
    int tid = threadIdx.x;
    int lane = tid & 63, w = tid >> 6;

    float m = -1e30f, s = 0.f;
    for (int i = tid; i < 4000; i += 256) {
        bf16x8 v = src[i];
        srow[i] = v;
        float f[8];
#pragma unroll
        for (int j = 0; j < 8; ++j) f[j] = bf2f((unsigned short)v[j]);
        float cm = f[0];
#pragma unroll
        for (int j = 1; j < 8; ++j) cm = fmaxf(cm, f[j]);
        if (cm > m) { s *= __expf(m - cm); m = cm; }
#pragma unroll
        for (int j = 0; j < 8; ++j) s += __expf(f[j] - m);
    }
#pragma unroll
    for (int off = 1; off < 64; off <<= 1) {
        float om = __shfl_xor(m, off, 64);
        float os = __shfl_xor(s, off, 64);
        float nm = fmaxf(m, om);
        s = s * __expf(m - nm) + os * __expf(om - nm);
        m = nm;
    }
    if (lane == 0) sred[w] = make_float2(m, s);
    __syncthreads();
    if (tid == 0) {
        float fm = sred[0].x, fs = sred[0].y;
#pragma unroll
        for (int k = 1; k < 4; ++k) {
            float om = sred[k].x, os = sred[k].y;
            float nm = fmaxf(fm, om);
            fs = fs * __expf(fm - nm) + os * __expf(om - nm);
            fm = nm;
        }
        sc = fm + logf(fs);
    }
    __syncthreads();
    float c = sc;
    for (int i = tid; i < 4000; i += 256) {
        bf16x8 v = srow[i];
        float4 o0, o1;
        o0.x = bf2f((unsigned short)v[0]) - c; o0.y = bf2f((unsigned short)v[1]) - c;
        o0.z = bf2f((unsigned short)v[2]) - c; o0.w = bf2f((unsigned short)v[3]) - c;
        o1.x = bf2f((unsigned short)v[4]) - c; o1.y = bf2f((unsigned short)v[5]) - c;
        o1.z = bf2f((unsigned short)v[6]) - c; o1.w = bf2f((unsigned short)v[7]) - c;
        ((float4*)dst)[i * 2] = o0;
        ((float4*)dst)[i * 2 + 1] = o1;
    }
}

// ---------------------------------------------------------------- fp32 fallback log-softmax
__global__ __launch_bounds__(256) void lsm_fused(float* __restrict__ out) {
    float4* p4 = (float4*)(out + (size_t)blockIdx.x * VOCABN);
    int tid = threadIdx.x;
    int lane = tid & 63, w = tid >> 6;
    __shared__ float2 sred[4];
    __shared__ float sc;

    float m = -1e30f, s = 0.f;
    for (int i = tid; i < VOCABN / 4; i += 256) {
        float4 v = p4[i];
        float cm = fmaxf(fmaxf(v.x, v.y), fmaxf(v.z, v.w));
        if (cm > m) { s *= __expf(m - cm); m = cm; }
        s += __expf(v.x - m) + __expf(v.y - m) + __expf(v.z - m) + __expf(v.w - m);
    }
#pragma unroll
    for (int off = 1; off < 64; off <<= 1) {
        float om = __shfl_xor(m, off, 64);
        float os = __shfl_xor(s, off, 64);
        float nm = fmaxf(m, om);
        s = s * __expf(m - nm) + os * __expf(om - nm);
        m = nm;
    }
    if (lane == 0) sred[w] = make_float2(m, s);
    __syncthreads();
    if (tid == 0) {
        float fm = sred[0].x, fs = sred[0].y;
#pragma unroll
        for (int k = 1; k < 4; ++k) {
            float om = sred[k].x, os = sred[k].y;
            float nm = fmaxf(fm, om);
            fs = fs * __expf(fm - nm) + os * __expf(om - nm);
            fm = nm;
        }
        sc = fm + logf(fs);
    }
    __syncthreads();
    float c = sc;
    for (int i = tid; i < VOCABN / 4; i += 256) {
        float4 v = p4[i];
        v.x -= c; v.y -= c; v.z -= c; v.w -= c;
        p4[i] = v;
    }
}

// ----------------------------------------------------------------
extern "C" void kernel_launch(void* const* d_in, const int* in_sizes, int n_in,
                              void* d_out, int out_size, void* d_ws, size_t ws_size,
                              hipStream_t stream) {
    const float* enc_h  = (const float*)d_in[1];
    const int*   target = (const int*)d_in[2];
    const float* emb    = (const float*)d_in[3];
    const float* w_ih   = (const float*)d_in[4];
    const float* w_hh   = (const float*)d_in[5];
    const float* b_ih   = (const float*)d_in[6];
    const float* b_hh   = (const float*)d_in[7];
    const float* out_w  = (const float*)d_in[8];
    const float* out_b  = (const float*)d_in[9];
    float* out = (float*)d_out;

    char* p0 = (char*)d_ws;
    char* p = p0;
    unsigned short* Xb   = (unsigned short*)p; p += (size_t)ROWS * HID * 2;
    unsigned short* Wih  = (unsigned short*)p; p += (size_t)G3 * HID * 2;
    unsigned short* OutW = (unsigned short*)p; p += (size_t)VOCABN * HID * 2;
    unsigned short* Hall = (unsigned short*)p; p += (size_t)ROWS_PAD * HID * 2;
    float* gi   = (float*)p; p += (size_t)ROWS * G3 * 4;
    unsigned short* Whhb = (unsigned short*)p; p += (size_t)G3 * HID * 2;
    unsigned short* h0b  = (unsigned short*)p; p += (size_t)BATCH * HID * 2;
    unsigned int* bar = (unsigned int*)p; p += 256 * sizeof(unsigned int);
    unsigned short* lscratch = (unsigned short*)p; p += (size_t)ROWS * VOCABN * 2;  // 122.88 MB
    const bool use_bf16 = ((size_t)(p - p0) <= ws_size);

    f32_to_bf16<<<768, 256, 0, stream>>>(w_ih, Wih, G3 * HID / 4);
    f32_to_bf16<<<768, 256, 0, stream>>>(w_hh, Whhb, G3 * HID / 4);
    f32_to_bf16<<<64, 256, 0, stream>>>(enc_h, h0b, BATCH * HID / 4);
    embed_relu_bf16<<<ROWS, 256, 0, stream>>>(target, emb, Xb);
    init_bar<<<1, 64, 0, stream>>>(bar);

    gemm_mfma_bt<<<dim3(G3 / 128, ROWS / 128), 256, 0, stream>>>(Xb, Wih, b_ih, gi, G3, HID);

    {
        const unsigned short* a0 = h0b;
        const float* a1 = enc_h;
        const unsigned short* a2 = Whhb;
        const float* a3 = b_hh;
        const float* a4 = gi;
        unsigned short* a5 = Hall;
        float* a6 = out + OUT_HID_OFF;
        unsigned int* a7 = bar;
        const float* a8 = out_w;
        unsigned short* a9 = OutW;
        void* args[] = {&a0, &a1, &a2, &a3, &a4, &a5, &a6, &a7, &a8, &a9};
        hipLaunchCooperativeKernel((void*)gru_persistent, dim3(256), dim3(256),
                                   args, 0, stream);
    }

    if (use_bf16) {
        gemm_logits256<true><<<1024, 512, 0, stream>>>(Hall, OutW, out_b, out, lscratch);
        lsm_fused_bf16<<<ROWS, 256, 0, stream>>>(lscratch, out);
    } else {
        gemm_logits256<false><<<1024, 512, 0, stream>>>(Hall, OutW, out_b, out, nullptr);
        lsm_fused<<<ROWS, 256, 0, stream>>>(out);
    }
}

// Round 19
// 499.865 us; speedup vs baseline: 3.0662x; 3.0662x over previous
//
#include <hip/hip_runtime.h>
#include <math.h>

#define T_STEPS 30
#define BATCH   64
#define HID     1024
#define VOCABN  32000
#define G3      3072
#define ROWS    (T_STEPS * BATCH)   // 1920
#define ROWS_PAD 2048
#define OUT_HID_OFF ((size_t)BATCH * T_STEPS * VOCABN)  // 61,440,000

typedef __attribute__((ext_vector_type(8))) short bf16x8;
typedef __attribute__((ext_vector_type(4))) float f32x4;

__device__ __forceinline__ unsigned short f2bf(float f) {
    union { float f; unsigned u; } x; x.f = f;
    unsigned r = x.u + 0x7fffu + ((x.u >> 16) & 1u);
    return (unsigned short)(r >> 16);
}
__device__ __forceinline__ float bf2f(unsigned short u) {
    union { unsigned u; float f; } x; x.u = (unsigned)u << 16;
    return x.f;
}

__device__ __forceinline__ void gld_lds16(const unsigned short* g, unsigned short* l) {
    __builtin_amdgcn_global_load_lds(
        (const __attribute__((address_space(1))) unsigned*)g,
        (__attribute__((address_space(3))) unsigned*)l, 16, 0, 0);
}

// ---------------------------------------------------------------- fp32 -> bf16 (RNE)
__global__ __launch_bounds__(256) void f32_to_bf16(const float* __restrict__ src,
                                                   unsigned short* __restrict__ dst, int n4) {
    int i = blockIdx.x * 256 + threadIdx.x;
    int stride = gridDim.x * 256;
    for (; i < n4; i += stride) {
        float4 v = ((const float4*)src)[i];
        ushort4 o;
        o.x = f2bf(v.x); o.y = f2bf(v.y); o.z = f2bf(v.z); o.w = f2bf(v.w);
        ((ushort4*)dst)[i] = o;
    }
}

// ---------------------------------------------------------------- X = relu(emb[tok]) -> bf16
__global__ __launch_bounds__(256) void embed_relu_bf16(const int* __restrict__ target,
                                                       const float* __restrict__ emb,
                                                       unsigned short* __restrict__ X) {
    int bid = blockIdx.x;           // t*64 + b
    int t = bid >> 6, b = bid & 63;
    int tok = (t == 0) ? 0 : target[b * T_STEPS + (t - 1)];
    const float4* src = (const float4*)(emb + (size_t)tok * HID);
    float4 v = src[threadIdx.x];
    ushort4 o;
    o.x = f2bf(fmaxf(v.x, 0.f)); o.y = f2bf(fmaxf(v.y, 0.f));
    o.z = f2bf(fmaxf(v.z, 0.f)); o.w = f2bf(fmaxf(v.w, 0.f));
    ((ushort4*)(X + (size_t)bid * HID))[threadIdx.x] = o;
}

// ---------------------------------------------------------------- barrier flags init
__global__ void init_bar(unsigned int* bar) {
    if (threadIdx.x < 64) bar[threadIdx.x] = 0u;
}

// ---------------------------------------------------------------- gi GEMM (128^2)
__global__ __launch_bounds__(256) void gemm_mfma_bt(const unsigned short* __restrict__ A,
                                                    const unsigned short* __restrict__ W,
                                                    const float* __restrict__ bias,
                                                    float* __restrict__ out,
                                                    int N, int K) {
    __shared__ unsigned short As[128 * 64];
    __shared__ unsigned short Bs[128 * 64];
    int tid  = threadIdx.x;
    int lane = tid & 63;
    int wid  = tid >> 6;
    int wm   = wid >> 1, wn = wid & 1;
    const int bM = blockIdx.y * 128;
    const int bN = blockIdx.x * 128;

    f32x4 acc[4][4];
#pragma unroll
    for (int i = 0; i < 4; ++i)
#pragma unroll
        for (int j = 0; j < 4; ++j) acc[i][j] = (f32x4){0.f, 0.f, 0.f, 0.f};

    int sr[4], sc[4];
#pragma unroll
    for (int q = 0; q < 4; ++q) {
        sr[q] = (wid * 4 + q) * 8 + (lane >> 3);
        sc[q] = (lane & 7) ^ (sr[q] & 7);
    }

    for (int kt = 0; kt < K; kt += 64) {
        __syncthreads();
#pragma unroll
        for (int q = 0; q < 4; ++q) {
            gld_lds16(A + (size_t)(bM + sr[q]) * K + kt + sc[q] * 8, As + (wid * 4 + q) * 512);
            gld_lds16(W + (size_t)(bN + sr[q]) * K + kt + sc[q] * 8, Bs + (wid * 4 + q) * 512);
        }
        __syncthreads();

#pragma unroll
        for (int ks = 0; ks < 2; ++ks) {
            bf16x8 a[4], b[4];
#pragma unroll
            for (int mf = 0; mf < 4; ++mf) {
                int r  = wm * 64 + mf * 16 + (lane & 15);
                int ch = (ks * 4 + (lane >> 4)) ^ (r & 7);
                a[mf] = *(const bf16x8*)(As + r * 64 + ch * 8);
            }
#pragma unroll
            for (int nf = 0; nf < 4; ++nf) {
                int r  = wn * 64 + nf * 16 + (lane & 15);
                int ch = (ks * 4 + (lane >> 4)) ^ (r & 7);
                b[nf] = *(const bf16x8*)(Bs + r * 64 + ch * 8);
            }
#pragma unroll
            for (int mf = 0; mf < 4; ++mf)
#pragma unroll
                for (int nf = 0; nf < 4; ++nf)
                    acc[mf][nf] = __builtin_amdgcn_mfma_f32_16x16x32_bf16(
                        a[mf], b[nf], acc[mf][nf], 0, 0, 0);
        }
    }

    int rif = (lane >> 4) * 4;
    int col = lane & 15;
#pragma unroll
    for (int mf = 0; mf < 4; ++mf) {
#pragma unroll
        for (int j = 0; j < 4; ++j) {
            int gr = bM + wm * 64 + mf * 16 + rif + j;
#pragma unroll
            for (int nf = 0; nf < 4; ++nf) {
                int gc = bN + wn * 64 + nf * 16 + col;
                out[(size_t)gr * N + gc] = acc[mf][nf][j] + bias[gc];
            }
        }
    }
}

// ---------------------------------------------------------------- logits GEMM: 256^2 tile,
// r17 2-slot counted-vmcnt ring + XCD panel-grouping (r18's remap), but with
// plain __launch_bounds__(512) -- NO min-waves arg: r18's (512,4) capped the
// unified VGPR/AGPR file at 128 and spilled the 128-AGPR accumulator to
// scratch (5.9 GB traffic). Grid 1024: d -> xcd=d&7, mt=(d>>3)&7, pg=d>>6,
// panel p=pg*8+xcd; all 8 M-tiles of a panel share d%8 => one XCD.
template <bool BF16OUT>
__global__ __launch_bounds__(512) void gemm_logits256(const unsigned short* __restrict__ A,
                                                      const unsigned short* __restrict__ W,
                                                      const float* __restrict__ bias,
                                                      float* __restrict__ out,
                                                      unsigned short* __restrict__ scratch) {
    __shared__ unsigned short As[2][256 * 32];   // 16 KB per slot
    __shared__ unsigned short Bs[2][256 * 32];
    int d   = blockIdx.x;
    int xcd = d & 7;
    int mt  = (d >> 3) & 7;
    int pg  = d >> 6;
    int p   = pg * 8 + xcd;
    if (p >= VOCABN / 256) return;     // 125 panels
    const int bM = mt * 256;
    const int bN = p * 256;

    int tid  = threadIdx.x;
    int lane = tid & 63;
    int wid  = tid >> 6;         // 0..7
    int wm   = wid >> 2;         // 0..1 -> 128 M-rows
    int wn   = wid & 3;          // 0..3 -> 64 N-cols
    int l15  = lane & 15, l4 = lane >> 4;

    size_t pA[2], pB[2];
    int ldst[2];
#pragma unroll
    for (int i = 0; i < 2; ++i) {
        int c = wid * 128 + i * 64 + lane;
        int r = c >> 2, cc = c & 3;
        int so = (cc ^ ((r >> 1) & 3)) * 8;
        pA[i] = (size_t)(bM + r) * HID + so;
        pB[i] = (size_t)(bN + r) * HID + so;
        ldst[i] = wid * 1024 + i * 512;
    }

    f32x4 acc[8][4];
#pragma unroll
    for (int i = 0; i < 8; ++i)
#pragma unroll
        for (int j = 0; j < 4; ++j) acc[i][j] = (f32x4){0.f, 0.f, 0.f, 0.f};

    int chsw = (l4 ^ ((l15 >> 1) & 3)) * 8;
    int aoff[8], boff[4];
#pragma unroll
    for (int mf = 0; mf < 8; ++mf) aoff[mf] = (wm * 128 + mf * 16 + l15) * 32 + chsw;
#pragma unroll
    for (int nf = 0; nf < 4; ++nf) boff[nf] = (wn * 64 + nf * 16 + l15) * 32 + chsw;

    auto issue = [&](int s) {
        int slot = s & 1;
#pragma unroll
        for (int i = 0; i < 2; ++i)
            gld_lds16(A + pA[i] + s * 32, &As[slot][ldst[i]]);
#pragma unroll
        for (int i = 0; i < 2; ++i)
            gld_lds16(W + pB[i] + s * 32, &Bs[slot][ldst[i]]);
    };

    issue(0); issue(1);          // 8 vmem instrs in flight per wave

#pragma unroll 1
    for (int s = 0; s < 32; ++s) {
        if (s < 31) asm volatile("s_waitcnt vmcnt(4)" ::: "memory");   // sub-tile s landed
        else        asm volatile("s_waitcnt vmcnt(0)" ::: "memory");
        __builtin_amdgcn_s_barrier();      // all waves: s landed
        asm volatile("" ::: "memory");
        __builtin_amdgcn_sched_barrier(0);

        int slot = s & 1;
        const unsigned short* ab = As[slot];
        const unsigned short* bb = Bs[slot];
        bf16x8 a[8], b[4];
#pragma unroll
        for (int mf = 0; mf < 8; ++mf) a[mf] = *(const bf16x8*)(ab + aoff[mf]);
#pragma unroll
        for (int nf = 0; nf < 4; ++nf) b[nf] = *(const bf16x8*)(bb + boff[nf]);
        __builtin_amdgcn_s_setprio(1);
#pragma unroll
        for (int mf = 0; mf < 8; ++mf)
#pragma unroll
            for (int nf = 0; nf < 4; ++nf)
                acc[mf][nf] = __builtin_amdgcn_mfma_f32_16x16x32_bf16(
                    a[mf], b[nf], acc[mf][nf], 0, 0, 0);
        __builtin_amdgcn_s_setprio(0);

        asm volatile("s_waitcnt lgkmcnt(0)" ::: "memory");  // this wave's slot reads done
        __builtin_amdgcn_s_barrier();      // all waves done reading slot s&1
        asm volatile("" ::: "memory");
        __builtin_amdgcn_sched_barrier(0);
        if (s < 30) issue(s + 2);          // overwrite slot s&1, lands by iter s+2
    }

    int col = l15;
    float b4[4];
#pragma unroll
    for (int nf = 0; nf < 4; ++nf) b4[nf] = bias[bN + wn * 64 + nf * 16 + col];
    int rif = l4 * 4;
#pragma unroll
    for (int mf = 0; mf < 8; ++mf) {
#pragma unroll
        for (int j = 0; j < 4; ++j) {
            int gr = bM + wm * 128 + mf * 16 + rif + j;
            if (gr < ROWS) {
                int t = gr >> 6, b_ = gr & 63;
                size_t rowoff = ((size_t)b_ * T_STEPS + t) * (size_t)VOCABN;
#pragma unroll
                for (int nf = 0; nf < 4; ++nf) {
                    float v = acc[mf][nf][j] + b4[nf];
                    int gc = bN + wn * 64 + nf * 16 + col;
                    if (BF16OUT) scratch[rowoff + gc] = f2bf(v);
                    else         out[rowoff + gc] = v;
                }
            }
        }
    }
}

// ---------------------------------------------------------------- persistent 30-step GRU
// (blocks 0-63 recurrence; 64-255 OutW convert hidden under recurrence)
__global__ __launch_bounds__(256, 1) void gru_persistent(
    const unsigned short* __restrict__ h0b,
    const float* __restrict__ enc_h,
    const unsigned short* __restrict__ Whh,
    const float* __restrict__ b_hh,
    const float* __restrict__ gi,
    unsigned short* __restrict__ Hall,
    float* __restrict__ h_final,
    unsigned int* __restrict__ flags,
    const float* __restrict__ outw_f32,
    unsigned short* __restrict__ outw_bf)
{
    __shared__ unsigned short Wlds[48 * 1024];   // 96 KB
    int tid  = threadIdx.x;

    if (blockIdx.x >= 64) {
        const int n4 = VOCABN * HID / 4;
        int i = (blockIdx.x - 64) * 256 + tid;
        const int stride = 192 * 256;
        for (; i < n4; i += stride) {
            float4 v = ((const float4*)outw_f32)[i];
            ushort4 o;
            o.x = f2bf(v.x); o.y = f2bf(v.y); o.z = f2bf(v.z); o.w = f2bf(v.w);
            ((ushort4*)outw_bf)[i] = o;
        }
        return;
    }

    int lane = tid & 63;
    int wq   = tid >> 6;
    int l15  = lane & 15, l4 = lane >> 4;
    int m0   = blockIdx.x * 16;
    int b    = wq * 16 + l15;
    int mb   = m0 + l4 * 4;

    for (int i = 0; i < 24; ++i) {
        int sb = wq * 24 + i;
        int kt = sb / 3, g = sb % 3;
        const unsigned short* src =
            Whh + (size_t)(g * HID + m0 + l15) * HID + kt * 32 + l4 * 8;
        gld_lds16(src, Wlds + sb * 512);
    }

    float hp[4];
    {
        float4 h4 = *(const float4*)(enc_h + (size_t)b * HID + mb);
        hp[0] = h4.x; hp[1] = h4.y; hp[2] = h4.z; hp[3] = h4.w;
    }
    float bhr[4], bhz[4], bhn[4];
    {
        float4 r4 = *(const float4*)(b_hh + mb);
        float4 z4 = *(const float4*)(b_hh + HID + mb);
        float4 n4 = *(const float4*)(b_hh + 2 * HID + mb);
        bhr[0]=r4.x; bhr[1]=r4.y; bhr[2]=r4.z; bhr[3]=r4.w;
        bhz[0]=z4.x; bhz[1]=z4.y; bhz[2]=z4.z; bhz[3]=z4.w;
        bhn[0]=n4.x; bhn[1]=n4.y; bhn[2]=n4.z; bhn[3]=n4.w;
    }
    __syncthreads();

    int arow16 = b * 128 + l4;

    for (int t = 0; t < T_STEPS; ++t) {
        const float* gib = gi + (size_t)t * BATCH * G3 + (size_t)b * G3;
        float4 giR = *(const float4*)(gib + mb);
        float4 giZ = *(const float4*)(gib + HID + mb);
        float4 giN = *(const float4*)(gib + 2 * HID + mb);
        float gr4[4] = {giR.x, giR.y, giR.z, giR.w};
        float gz4[4] = {giZ.x, giZ.y, giZ.z, giZ.w};
        float gn4[4] = {giN.x, giN.y, giN.z, giN.w};

        if (t > 0) {
            if (tid < 64) {
                while (__hip_atomic_load(flags + tid, __ATOMIC_RELAXED,
                                         __HIP_MEMORY_SCOPE_AGENT) < (unsigned)t) {}
            }
            __builtin_amdgcn_sched_barrier(0);
            __syncthreads();
            asm volatile("" ::: "memory");
        }

        const unsigned short* Asrc = (t == 0) ? h0b : (Hall + (size_t)(t - 1) * BATCH * HID);
        const bf16x8* A16 = (const bf16x8*)Asrc;

        bf16x8 hreg[32];
#pragma unroll
        for (int kt = 0; kt < 32; ++kt) hreg[kt] = A16[arow16 + kt * 4];

        f32x4 acc[3];
#pragma unroll
        for (int g = 0; g < 3; ++g) acc[g] = (f32x4){0.f, 0.f, 0.f, 0.f};

#pragma unroll
        for (int kt = 0; kt < 32; ++kt) {
#pragma unroll
            for (int g = 0; g < 3; ++g) {
                bf16x8 wfrag = *(const bf16x8*)(Wlds + ((size_t)(kt * 3 + g) * 64 + lane) * 8);
                acc[g] = __builtin_amdgcn_mfma_f32_16x16x32_bf16(wfrag, hreg[kt], acc[g], 0, 0, 0);
            }
        }

        unsigned long long pack = 0;
#pragma unroll
        for (int j = 0; j < 4; ++j) {
            float r = 1.f / (1.f + __expf(-(gr4[j] + acc[0][j] + bhr[j])));
            float z = 1.f / (1.f + __expf(-(gz4[j] + acc[1][j] + bhz[j])));
            float e2 = __expf(2.f * (gn4[j] + r * (acc[2][j] + bhn[j])));
            float n = 1.f - 2.f / (e2 + 1.f);   // tanh
            float hnew = (1.f - z) * n + z * hp[j];
            hp[j] = hnew;
            pack |= (unsigned long long)f2bf(hnew) << (16 * j);
        }
        __hip_atomic_store((unsigned long long*)(Hall + (size_t)t * BATCH * HID +
                                                 (size_t)b * HID + mb),
                           pack, __ATOMIC_RELAXED, __HIP_MEMORY_SCOPE_AGENT);
        if (t == T_STEPS - 1) {
            float4 hf = {hp[0], hp[1], hp[2], hp[3]};
            *(float4*)(h_final + (size_t)b * HID + mb) = hf;
        }

        if (t < T_STEPS - 1) {
            __syncthreads();
            if (tid == 0)
                __hip_atomic_store(flags + blockIdx.x, (unsigned)(t + 1),
                                   __ATOMIC_RELAXED, __HIP_MEMORY_SCOPE_AGENT);
        }
    }
}

// ---------------------------------------------------------------- fused log-softmax from bf16
__global__ __launch_bounds__(256) void lsm_fused_bf16(const unsigned short* __restrict__ scratch,
                                                      float* __restrict__ out) {
    __shared__ bf16x8 srow[4000];    // 64 KB
    __shared__ float2 sred[4];
    __shared__ float sc;
    const bf16x8* src = (const bf16x8*)(scratch + (size_t)blockIdx.x * VOCABN);
    float* dst = out + (size_t)blockIdx.x * VOCABN;
    int tid = threadIdx.x;
    int lane = tid & 63, w = tid >> 6;

    float m = -1e30f, s = 0.f;
    for (int i = tid; i < 4000; i += 256) {
        bf16x8 v = src[i];
        srow[i] = v;
        float f[8];
#pragma unroll
        for (int j = 0; j < 8; ++j) f[j] = bf2f((unsigned short)v[j]);
        float cm = f[0];
#pragma unroll
        for (int j = 1; j < 8; ++j) cm = fmaxf(cm, f[j]);
        if (cm > m) { s *= __expf(m - cm); m = cm; }
#pragma unroll
        for (int j = 0; j < 8; ++j) s += __expf(f[j] - m);
    }
#pragma unroll
    for (int off = 1; off < 64; off <<= 1) {
        float om = __shfl_xor(m, off, 64);
        float os = __shfl_xor(s, off, 64);
        float nm = fmaxf(m, om);
        s = s * __expf(m - nm) + os * __expf(om - nm);
        m = nm;
    }
    if (lane == 0) sred[w] = make_float2(m, s);
    __syncthreads();
    if (tid == 0) {
        float fm = sred[0].x, fs = sred[0].y;
#pragma unroll
        for (int k = 1; k < 4; ++k) {
            float om = sred[k].x, os = sred[k].y;
            float nm = fmaxf(fm, om);
            fs = fs * __expf(fm - nm) + os * __expf(om - nm);
            fm = nm;
        }
        sc = fm + logf(fs);
    }
    __syncthreads();
    float c = sc;
    for (int i = tid; i < 4000; i += 256) {
        bf16x8 v = srow[i];
        float4 o0, o1;
        o0.x = bf2f((unsigned short)v[0]) - c; o0.y = bf2f((unsigned short)v[1]) - c;
        o0.z = bf2f((unsigned short)v[2]) - c; o0.w = bf2f((unsigned short)v[3]) - c;
        o1.x = bf2f((unsigned short)v[4]) - c; o1.y = bf2f((unsigned short)v[5]) - c;
        o1.z = bf2f((unsigned short)v[6]) - c; o1.w = bf2f((unsigned short)v[7]) - c;
        ((float4*)dst)[i * 2] = o0;
        ((float4*)dst)[i * 2 + 1] = o1;
    }
}

// ---------------------------------------------------------------- fp32 fallback log-softmax
__global__ __launch_bounds__(256) void lsm_fused(float* __restrict__ out) {
    float4* p4 = (float4*)(out + (size_t)blockIdx.x * VOCABN);
    int tid = threadIdx.x;
    int lane = tid & 63, w = tid >> 6;
    __shared__ float2 sred[4];
    __shared__ float sc;

    float m = -1e30f, s = 0.f;
    for (int i = tid; i < VOCABN / 4; i += 256) {
        float4 v = p4[i];
        float cm = fmaxf(fmaxf(v.x, v.y), fmaxf(v.z, v.w));
        if (cm > m) { s *= __expf(m - cm); m = cm; }
        s += __expf(v.x - m) + __expf(v.y - m) + __expf(v.z - m) + __expf(v.w - m);
    }
#pragma unroll
    for (int off = 1; off < 64; off <<= 1) {
        float om = __shfl_xor(m, off, 64);
        float os = __shfl_xor(s, off, 64);
        float nm = fmaxf(m, om);
        s = s * __expf(m - nm) + os * __expf(om - nm);
        m = nm;
    }
    if (lane == 0) sred[w] = make_float2(m, s);
    __syncthreads();
    if (tid == 0) {
        float fm = sred[0].x, fs = sred[0].y;
#pragma unroll
        for (int k = 1; k < 4; ++k) {
            float om = sred[k].x, os = sred[k].y;
            float nm = fmaxf(fm, om);
            fs = fs * __expf(fm - nm) + os * __expf(om - nm);
            fm = nm;
        }
        sc = fm + logf(fs);
    }
    __syncthreads();
    float c = sc;
    for (int i = tid; i < VOCABN / 4; i += 256) {
        float4 v = p4[i];
        v.x -= c; v.y -= c; v.z -= c; v.w -= c;
        p4[i] = v;
    }
}

// ----------------------------------------------------------------
extern "C" void kernel_launch(void* const* d_in, const int* in_sizes, int n_in,
                              void* d_out, int out_size, void* d_ws, size_t ws_size,
                              hipStream_t stream) {
    const float* enc_h  = (const float*)d_in[1];
    const int*   target = (const int*)d_in[2];
    const float* emb    = (const float*)d_in[3];
    const float* w_ih   = (const float*)d_in[4];
    const float* w_hh   = (const float*)d_in[5];
    const float* b_ih   = (const float*)d_in[6];
    const float* b_hh   = (const float*)d_in[7];
    const float* out_w  = (const float*)d_in[8];
    const float* out_b  = (const float*)d_in[9];
    float* out = (float*)d_out;

    char* p0 = (char*)d_ws;
    char* p = p0;
    unsigned short* Xb   = (unsigned short*)p; p += (size_t)ROWS * HID * 2;
    unsigned short* Wih  = (unsigned short*)p; p += (size_t)G3 * HID * 2;
    unsigned short* OutW = (unsigned short*)p; p += (size_t)VOCABN * HID * 2;
    unsigned short* Hall = (unsigned short*)p; p += (size_t)ROWS_PAD * HID * 2;
    float* gi   = (float*)p; p += (size_t)ROWS * G3 * 4;
    unsigned short* Whhb = (unsigned short*)p; p += (size_t)G3 * HID * 2;
    unsigned short* h0b  = (unsigned short*)p; p += (size_t)BATCH * HID * 2;
    unsigned int* bar = (unsigned int*)p; p += 256 * sizeof(unsigned int);
    unsigned short* lscratch = (unsigned short*)p; p += (size_t)ROWS * VOCABN * 2;  // 122.88 MB
    const bool use_bf16 = ((size_t)(p - p0) <= ws_size);

    f32_to_bf16<<<768, 256, 0, stream>>>(w_ih, Wih, G3 * HID / 4);
    f32_to_bf16<<<768, 256, 0, stream>>>(w_hh, Whhb, G3 * HID / 4);
    f32_to_bf16<<<64, 256, 0, stream>>>(enc_h, h0b, BATCH * HID / 4);
    embed_relu_bf16<<<ROWS, 256, 0, stream>>>(target, emb, Xb);
    init_bar<<<1, 64, 0, stream>>>(bar);

    gemm_mfma_bt<<<dim3(G3 / 128, ROWS / 128), 256, 0, stream>>>(Xb, Wih, b_ih, gi, G3, HID);

    {
        const unsigned short* a0 = h0b;
        const float* a1 = enc_h;
        const unsigned short* a2 = Whhb;
        const float* a3 = b_hh;
        const float* a4 = gi;
        unsigned short* a5 = Hall;
        float* a6 = out + OUT_HID_OFF;
        unsigned int* a7 = bar;
        const float* a8 = out_w;
        unsigned short* a9 = OutW;
        void* args[] = {&a0, &a1, &a2, &a3, &a4, &a5, &a6, &a7, &a8, &a9};
        hipLaunchCooperativeKernel((void*)gru_persistent, dim3(256), dim3(256),
                                   args, 0, stream);
    }

    if (use_bf16) {
        gemm_logits256<true><<<1024, 512, 0, stream>>>(Hall, OutW, out_b, out, lscratch);
        lsm_fused_bf16<<<ROWS, 256, 0, stream>>>(lscratch, out);
    } else {
        gemm_logits256<false><<<1024, 512, 0, stream>>>(Hall, OutW, out_b, out, nullptr);
        lsm_fused<<<ROWS, 256, 0, stream>>>(out);
    }
}

// Round 21
// 441.044 us; speedup vs baseline: 3.4752x; 1.1334x over previous
//
#include <hip/hip_runtime.h>
#include <math.h>

#define T_STEPS 30
#define BATCH   64
#define HID     1024
#define VOCABN  32000
#define G3      3072
#define ROWS    (T_STEPS * BATCH)   // 1920
#define ROWS_PAD 2048
#define OUT_HID_OFF ((size_t)BATCH * T_STEPS * VOCABN)  // 61,440,000
#define N_ITEMS 1000                // 8 M-tiles x 125 panels

typedef __attribute__((ext_vector_type(8))) short bf16x8;
typedef __attribute__((ext_vector_type(4))) float f32x4;

__device__ __forceinline__ unsigned short f2bf(float f) {
    union { float f; unsigned u; } x; x.f = f;
    unsigned r = x.u + 0x7fffu + ((x.u >> 16) & 1u);
    return (unsigned short)(r >> 16);
}
__device__ __forceinline__ float bf2f(unsigned short u) {
    union { unsigned u; float f; } x; x.u = (unsigned)u << 16;
    return x.f;
}

__device__ __forceinline__ void gld_lds16(const unsigned short* g, unsigned short* l) {
    __builtin_amdgcn_global_load_lds(
        (const __attribute__((address_space(1))) unsigned*)g,
        (__attribute__((address_space(3))) unsigned*)l, 16, 0, 0);
}

// ---------------------------------------------------------------- fp32 -> bf16 (RNE)
__global__ __launch_bounds__(256) void f32_to_bf16(const float* __restrict__ src,
                                                   unsigned short* __restrict__ dst, int n4) {
    int i = blockIdx.x * 256 + threadIdx.x;
    int stride = gridDim.x * 256;
    for (; i < n4; i += stride) {
        float4 v = ((const float4*)src)[i];
        ushort4 o;
        o.x = f2bf(v.x); o.y = f2bf(v.y); o.z = f2bf(v.z); o.w = f2bf(v.w);
        ((ushort4*)dst)[i] = o;
    }
}

// ---------------------------------------------------------------- X = relu(emb[tok]) -> bf16
__global__ __launch_bounds__(256) void embed_relu_bf16(const int* __restrict__ target,
                                                       const float* __restrict__ emb,
                                                       unsigned short* __restrict__ X) {
    int bid = blockIdx.x;           // t*64 + b
    int t = bid >> 6, b = bid & 63;
    int tok = (t == 0) ? 0 : target[b * T_STEPS + (t - 1)];
    const float4* src = (const float4*)(emb + (size_t)tok * HID);
    float4 v = src[threadIdx.x];
    ushort4 o;
    o.x = f2bf(fmaxf(v.x, 0.f)); o.y = f2bf(fmaxf(v.y, 0.f));
    o.z = f2bf(fmaxf(v.z, 0.f)); o.w = f2bf(fmaxf(v.w, 0.f));
    ((ushort4*)(X + (size_t)bid * HID))[threadIdx.x] = o;
}

// ---------------------------------------------------------------- flags + counters init
__global__ void init_bar(unsigned int* bar) {
    if (threadIdx.x < 128) bar[threadIdx.x] = 0u;
}

// ---------------------------------------------------------------- gi GEMM (128^2)
__global__ __launch_bounds__(256) void gemm_mfma_bt(const unsigned short* __restrict__ A,
                                                    const unsigned short* __restrict__ W,
                                                    const float* __restrict__ bias,
                                                    float* __restrict__ out,
                                                    int N, int K) {
    __shared__ unsigned short As[128 * 64];
    __shared__ unsigned short Bs[128 * 64];
    int tid  = threadIdx.x;
    int lane = tid & 63;
    int wid  = tid >> 6;
    int wm   = wid >> 1, wn = wid & 1;
    const int bM = blockIdx.y * 128;
    const int bN = blockIdx.x * 128;

    f32x4 acc[4][4];
#pragma unroll
    for (int i = 0; i < 4; ++i)
#pragma unroll
        for (int j = 0; j < 4; ++j) acc[i][j] = (f32x4){0.f, 0.f, 0.f, 0.f};

    int sr[4], sc[4];
#pragma unroll
    for (int q = 0; q < 4; ++q) {
        sr[q] = (wid * 4 + q) * 8 + (lane >> 3);
        sc[q] = (lane & 7) ^ (sr[q] & 7);
    }

    for (int kt = 0; kt < K; kt += 64) {
        __syncthreads();
#pragma unroll
        for (int q = 0; q < 4; ++q) {
            gld_lds16(A + (size_t)(bM + sr[q]) * K + kt + sc[q] * 8, As + (wid * 4 + q) * 512);
            gld_lds16(W + (size_t)(bN + sr[q]) * K + kt + sc[q] * 8, Bs + (wid * 4 + q) * 512);
        }
        __syncthreads();

#pragma unroll
        for (int ks = 0; ks < 2; ++ks) {
            bf16x8 a[4], b[4];
#pragma unroll
            for (int mf = 0; mf < 4; ++mf) {
                int r  = wm * 64 + mf * 16 + (lane & 15);
                int ch = (ks * 4 + (lane >> 4)) ^ (r & 7);
                a[mf] = *(const bf16x8*)(As + r * 64 + ch * 8);
            }
#pragma unroll
            for (int nf = 0; nf < 4; ++nf) {
                int r  = wn * 64 + nf * 16 + (lane & 15);
                int ch = (ks * 4 + (lane >> 4)) ^ (r & 7);
                b[nf] = *(const bf16x8*)(Bs + r * 64 + ch * 8);
            }
#pragma unroll
            for (int mf = 0; mf < 4; ++mf)
#pragma unroll
                for (int nf = 0; nf < 4; ++nf)
                    acc[mf][nf] = __builtin_amdgcn_mfma_f32_16x16x32_bf16(
                        a[mf], b[nf], acc[mf][nf], 0, 0, 0);
        }
    }

    int rif = (lane >> 4) * 4;
    int col = lane & 15;
#pragma unroll
    for (int mf = 0; mf < 4; ++mf) {
#pragma unroll
        for (int j = 0; j < 4; ++j) {
            int gr = bM + wm * 64 + mf * 16 + rif + j;
#pragma unroll
            for (int nf = 0; nf < 4; ++nf) {
                int gc = bN + wn * 64 + nf * 16 + col;
                out[(size_t)gr * N + gc] = acc[mf][nf][j] + bias[gc];
            }
        }
    }
}

// ---------------------------------------------------------------- logits GEMM tile body
template <bool BF16OUT>
__device__ void gemm_tile(int mt, int p,
                          const unsigned short* __restrict__ A,
                          const unsigned short* __restrict__ W,
                          const float* __restrict__ bias,
                          float* __restrict__ out,
                          unsigned short* __restrict__ scratch,
                          unsigned short* AsB, unsigned short* BsB) {
    const int bM = mt * 256;
    const int bN = p * 256;
    int tid  = threadIdx.x;
    int lane = tid & 63;
    int wid  = tid >> 6;         // 0..7
    int wm   = wid >> 2;
    int wn   = wid & 3;
    int l15  = lane & 15, l4 = lane >> 4;

    size_t pA[2], pB[2];
    int ldst[2];
#pragma unroll
    for (int i = 0; i < 2; ++i) {
        int c = wid * 128 + i * 64 + lane;
        int r = c >> 2, cc = c & 3;
        int so = (cc ^ ((r >> 1) & 3)) * 8;
        pA[i] = (size_t)(bM + r) * HID + so;
        pB[i] = (size_t)(bN + r) * HID + so;
        ldst[i] = wid * 1024 + i * 512;
    }

    f32x4 acc[8][4];
#pragma unroll
    for (int i = 0; i < 8; ++i)
#pragma unroll
        for (int j = 0; j < 4; ++j) acc[i][j] = (f32x4){0.f, 0.f, 0.f, 0.f};

    int chsw = (l4 ^ ((l15 >> 1) & 3)) * 8;
    int aoff[8], boff[4];
#pragma unroll
    for (int mf = 0; mf < 8; ++mf) aoff[mf] = (wm * 128 + mf * 16 + l15) * 32 + chsw;
#pragma unroll
    for (int nf = 0; nf < 4; ++nf) boff[nf] = (wn * 64 + nf * 16 + l15) * 32 + chsw;

    auto issue = [&](int s) {
        int slot = s & 1;
#pragma unroll
        for (int i = 0; i < 2; ++i)
            gld_lds16(A + pA[i] + s * 32, AsB + slot * 8192 + ldst[i]);
#pragma unroll
        for (int i = 0; i < 2; ++i)
            gld_lds16(W + pB[i] + s * 32, BsB + slot * 8192 + ldst[i]);
    };

    issue(0); issue(1);

#pragma unroll 1
    for (int s = 0; s < 32; ++s) {
        if (s < 31) asm volatile("s_waitcnt vmcnt(4)" ::: "memory");
        else        asm volatile("s_waitcnt vmcnt(0)" ::: "memory");
        __builtin_amdgcn_s_barrier();
        asm volatile("" ::: "memory");
        __builtin_amdgcn_sched_barrier(0);

        int slot = s & 1;
        const unsigned short* ab = AsB + slot * 8192;
        const unsigned short* bb = BsB + slot * 8192;
        bf16x8 a[8], b[4];
#pragma unroll
        for (int mf = 0; mf < 8; ++mf) a[mf] = *(const bf16x8*)(ab + aoff[mf]);
#pragma unroll
        for (int nf = 0; nf < 4; ++nf) b[nf] = *(const bf16x8*)(bb + boff[nf]);
        __builtin_amdgcn_s_setprio(1);
#pragma unroll
        for (int mf = 0; mf < 8; ++mf)
#pragma unroll
            for (int nf = 0; nf < 4; ++nf)
                acc[mf][nf] = __builtin_amdgcn_mfma_f32_16x16x32_bf16(
                    a[mf], b[nf], acc[mf][nf], 0, 0, 0);
        __builtin_amdgcn_s_setprio(0);

        asm volatile("s_waitcnt lgkmcnt(0)" ::: "memory");
        __builtin_amdgcn_s_barrier();
        asm volatile("" ::: "memory");
        __builtin_amdgcn_sched_barrier(0);
        if (s < 30) issue(s + 2);
    }

    int col = l15;
    float b4[4];
#pragma unroll
    for (int nf = 0; nf < 4; ++nf) b4[nf] = bias[bN + wn * 64 + nf * 16 + col];
    int rif = l4 * 4;
#pragma unroll
    for (int mf = 0; mf < 8; ++mf) {
#pragma unroll
        for (int j = 0; j < 4; ++j) {
            int gr = bM + wm * 128 + mf * 16 + rif + j;
            if (gr < ROWS) {
                int t = gr >> 6, b_ = gr & 63;
                size_t rowoff = ((size_t)b_ * T_STEPS + t) * (size_t)VOCABN;
#pragma unroll
                for (int nf = 0; nf < 4; ++nf) {
                    float v = acc[mf][nf][j] + b4[nf];
                    int gc = bN + wn * 64 + nf * 16 + col;
                    if (BF16OUT) scratch[rowoff + gc] = f2bf(v);
                    else         out[rowoff + gc] = v;
                }
            }
        }
    }
}

// ---------------------------------------------------------------- fused cooperative kernel
// Blocks 0-63: recurrence (waves 0-3) + per-step flags (incl. t=29 -> 30).
// Blocks 64-255: OutW convert via 8B sc1 relaxed atomic stores (write-through
// to LLC: cross-XCD-visible), then signal convdone (ctr[1]) after the
// __syncthreads vmcnt drain. ALL blocks gate the steal loop on convdone==192
// (fixes r20's race: plain-store dirty L2 lines + no completion ordering).
template <bool BF16OUT>
__global__ __launch_bounds__(512, 1) void fused_coop(
    const unsigned short* __restrict__ h0b,
    const float* __restrict__ enc_h,
    const unsigned short* __restrict__ Whh,
    const float* __restrict__ b_hh,
    const float* __restrict__ gi,
    unsigned short* __restrict__ Hall,
    float* __restrict__ h_final,
    unsigned int* __restrict__ flags,     // [64]
    unsigned int* __restrict__ ctr,       // [0]=work counter, [1]=convdone
    const float* __restrict__ outw_f32,
    unsigned short* __restrict__ outw_bf,
    const float* __restrict__ out_b,
    float* __restrict__ out,
    unsigned short* __restrict__ lscratch)
{
    __shared__ unsigned short smem[48 * 1024];   // 96 KB union
    __shared__ int sitem;
    int tid  = threadIdx.x;
    int bidx = blockIdx.x;

    if (bidx >= 64) {
        // -------- OutW convert: sc1 write-through stores (LLC-visible)
        const int n8 = VOCABN * HID / 4;      // 8-byte units
        int i = (bidx - 64) * 512 + tid;
        const int stride = 192 * 512;
        for (; i < n8; i += stride) {
            float4 v = ((const float4*)outw_f32)[i];
            unsigned long long pk =
                (unsigned long long)f2bf(v.x) |
                ((unsigned long long)f2bf(v.y) << 16) |
                ((unsigned long long)f2bf(v.z) << 32) |
                ((unsigned long long)f2bf(v.w) << 48);
            __hip_atomic_store((unsigned long long*)outw_bf + i, pk,
                               __ATOMIC_RELAXED, __HIP_MEMORY_SCOPE_AGENT);
        }
        __syncthreads();   // vmcnt(0): this block's sc1 stores ACKed at LLC
        if (tid == 0)
            __hip_atomic_fetch_add(ctr + 1, 1u, __ATOMIC_RELAXED,
                                   __HIP_MEMORY_SCOPE_AGENT);
    } else {
        // -------- 30-step recurrence (waves 0-3 active; 4-7 barrier-match)
        int lane = tid & 63;
        int wq   = tid >> 6;
        bool act = (wq < 4);
        int l15  = lane & 15, l4 = lane >> 4;
        int m0   = bidx * 16;
        int b    = (wq & 3) * 16 + l15;
        int mb   = m0 + l4 * 4;

        if (act) {
            for (int i = 0; i < 24; ++i) {
                int sb = wq * 24 + i;
                int kt = sb / 3, g = sb % 3;
                const unsigned short* src =
                    Whh + (size_t)(g * HID + m0 + l15) * HID + kt * 32 + l4 * 8;
                gld_lds16(src, smem + sb * 512);
            }
        }

        float hp[4] = {0.f, 0.f, 0.f, 0.f};
        float bhr[4], bhz[4], bhn[4];
        if (act) {
            float4 h4 = *(const float4*)(enc_h + (size_t)b * HID + mb);
            hp[0] = h4.x; hp[1] = h4.y; hp[2] = h4.z; hp[3] = h4.w;
            float4 r4 = *(const float4*)(b_hh + mb);
            float4 z4 = *(const float4*)(b_hh + HID + mb);
            float4 n4 = *(const float4*)(b_hh + 2 * HID + mb);
            bhr[0]=r4.x; bhr[1]=r4.y; bhr[2]=r4.z; bhr[3]=r4.w;
            bhz[0]=z4.x; bhz[1]=z4.y; bhz[2]=z4.z; bhz[3]=z4.w;
            bhn[0]=n4.x; bhn[1]=n4.y; bhn[2]=n4.z; bhn[3]=n4.w;
        }
        __syncthreads();   // W panel ready

        int arow16 = b * 128 + l4;

        for (int t = 0; t < T_STEPS; ++t) {
            float gr4[4], gz4[4], gn4[4];
            if (act) {
                const float* gib = gi + (size_t)t * BATCH * G3 + (size_t)b * G3;
                float4 giR = *(const float4*)(gib + mb);
                float4 giZ = *(const float4*)(gib + HID + mb);
                float4 giN = *(const float4*)(gib + 2 * HID + mb);
                gr4[0]=giR.x; gr4[1]=giR.y; gr4[2]=giR.z; gr4[3]=giR.w;
                gz4[0]=giZ.x; gz4[1]=giZ.y; gz4[2]=giZ.z; gz4[3]=giZ.w;
                gn4[0]=giN.x; gn4[1]=giN.y; gn4[2]=giN.z; gn4[3]=giN.w;
            }

            if (t > 0) {
                if (tid < 64) {
                    while (__hip_atomic_load(flags + tid, __ATOMIC_RELAXED,
                                             __HIP_MEMORY_SCOPE_AGENT) < (unsigned)t) {}
                }
                __builtin_amdgcn_sched_barrier(0);
                __syncthreads();
                asm volatile("" ::: "memory");
            }

            if (act) {
                const unsigned short* Asrc =
                    (t == 0) ? h0b : (Hall + (size_t)(t - 1) * BATCH * HID);
                const bf16x8* A16 = (const bf16x8*)Asrc;

                bf16x8 hreg[32];
#pragma unroll
                for (int kt = 0; kt < 32; ++kt) hreg[kt] = A16[arow16 + kt * 4];

                f32x4 acc[3];
#pragma unroll
                for (int g = 0; g < 3; ++g) acc[g] = (f32x4){0.f, 0.f, 0.f, 0.f};

#pragma unroll
                for (int kt = 0; kt < 32; ++kt) {
#pragma unroll
                    for (int g = 0; g < 3; ++g) {
                        bf16x8 wfrag =
                            *(const bf16x8*)(smem + ((size_t)(kt * 3 + g) * 64 + lane) * 8);
                        acc[g] = __builtin_amdgcn_mfma_f32_16x16x32_bf16(
                            wfrag, hreg[kt], acc[g], 0, 0, 0);
                    }
                }

                unsigned long long pack = 0;
#pragma unroll
                for (int j = 0; j < 4; ++j) {
                    float r = 1.f / (1.f + __expf(-(gr4[j] + acc[0][j] + bhr[j])));
                    float z = 1.f / (1.f + __expf(-(gz4[j] + acc[1][j] + bhz[j])));
                    float e2 = __expf(2.f * (gn4[j] + r * (acc[2][j] + bhn[j])));
                    float n = 1.f - 2.f / (e2 + 1.f);   // tanh
                    float hnew = (1.f - z) * n + z * hp[j];
                    hp[j] = hnew;
                    pack |= (unsigned long long)f2bf(hnew) << (16 * j);
                }
                __hip_atomic_store((unsigned long long*)(Hall + (size_t)t * BATCH * HID +
                                                         (size_t)b * HID + mb),
                                   pack, __ATOMIC_RELAXED, __HIP_MEMORY_SCOPE_AGENT);
                if (t == T_STEPS - 1) {
                    float4 hf = {hp[0], hp[1], hp[2], hp[3]};
                    *(float4*)(h_final + (size_t)b * HID + mb) = hf;
                }
            }

            __syncthreads();   // all sc1 h-stores vmcnt-drained (all waves)
            if (tid == 0)
                __hip_atomic_store(flags + bidx, (unsigned)(t + 1),
                                   __ATOMIC_RELAXED, __HIP_MEMORY_SCOPE_AGENT);
        }
    }

    // -------- gate: all 192 convert blocks done (OutW visible at LLC)
    if (tid == 0) {
        while (__hip_atomic_load(ctr + 1, __ATOMIC_RELAXED,
                                 __HIP_MEMORY_SCOPE_AGENT) < 192u) {}
    }
    __builtin_amdgcn_sched_barrier(0);
    __syncthreads();
    asm volatile("" ::: "memory");

    // -------- logits work-stealing loop (all 256 blocks)
    for (;;) {
        __syncthreads();                // protect sitem + LDS slot reuse
        if (tid == 0) sitem = (int)atomicAdd(ctr, 1u);
        __syncthreads();
        int item = sitem;
        if (item >= N_ITEMS) break;
        int mt = item / 125;
        int p  = item - mt * 125;
        unsigned need = (unsigned)(mt * 4 + 4);
        if (need > 30u) need = 30u;
        if (tid < 64) {
            while (__hip_atomic_load(flags + tid, __ATOMIC_RELAXED,
                                     __HIP_MEMORY_SCOPE_AGENT) < need) {}
        }
        __builtin_amdgcn_sched_barrier(0);
        __syncthreads();
        asm volatile("" ::: "memory");
        gemm_tile<BF16OUT>(mt, p, Hall, outw_bf, out_b, out, lscratch,
                           smem, smem + 16384);
    }
}

// ---------------------------------------------------------------- fused log-softmax from bf16
__global__ __launch_bounds__(256) void lsm_fused_bf16(const unsigned short* __restrict__ scratch,
                                                      float* __restrict__ out) {
    __shared__ bf16x8 srow[4000];    // 64 KB
    __shared__ float2 sred[4];
    __shared__ float sc;
    const bf16x8* src = (const bf16x8*)(scratch + (size_t)blockIdx.x * VOCABN);
    float* dst = out + (size_t)blockIdx.x * VOCABN;
    int tid = threadIdx.x;
    int lane = tid & 63, w = tid >> 6;

    float m = -1e30f, s = 0.f;
    for (int i = tid; i < 4000; i += 256) {
        bf16x8 v = src[i];
        srow[i] = v;
        float f[8];
#pragma unroll
        for (int j = 0; j < 8; ++j) f[j] = bf2f((unsigned short)v[j]);
        float cm = f[0];
#pragma unroll
        for (int j = 1; j < 8; ++j) cm = fmaxf(cm, f[j]);
        if (cm > m) { s *= __expf(m - cm); m = cm; }
#pragma unroll
        for (int j = 0; j < 8; ++j) s += __expf(f[j] - m);
    }
#pragma unroll
    for (int off = 1; off < 64; off <<= 1) {
        float om = __shfl_xor(m, off, 64);
        float os = __shfl_xor(s, off, 64);
        float nm = fmaxf(m, om);
        s = s * __expf(m - nm) + os * __expf(om - nm);
        m = nm;
    }
    if (lane == 0) sred[w] = make_float2(m, s);
    __syncthreads();
    if (tid == 0) {
        float fm = sred[0].x, fs = sred[0].y;
#pragma unroll
        for (int k = 1; k < 4; ++k) {
            float om = sred[k].x, os = sred[k].y;
            float nm = fmaxf(fm, om);
            fs = fs * __expf(fm - nm) + os * __expf(om - nm);
            fm = nm;
        }
        sc = fm + logf(fs);
    }
    __syncthreads();
    float c = sc;
    for (int i = tid; i < 4000; i += 256) {
        bf16x8 v = srow[i];
        float4 o0, o1;
        o0.x = bf2f((unsigned short)v[0]) - c; o0.y = bf2f((unsigned short)v[1]) - c;
        o0.z = bf2f((unsigned short)v[2]) - c; o0.w = bf2f((unsigned short)v[3]) - c;
        o1.x = bf2f((unsigned short)v[4]) - c; o1.y = bf2f((unsigned short)v[5]) - c;
        o1.z = bf2f((unsigned short)v[6]) - c; o1.w = bf2f((unsigned short)v[7]) - c;
        ((float4*)dst)[i * 2] = o0;
        ((float4*)dst)[i * 2 + 1] = o1;
    }
}

// ---------------------------------------------------------------- fp32 fallback log-softmax
__global__ __launch_bounds__(256) void lsm_fused(float* __restrict__ out) {
    float4* p4 = (float4*)(out + (size_t)blockIdx.x * VOCABN);
    int tid = threadIdx.x;
    int lane = tid & 63, w = tid >> 6;
    __shared__ float2 sred[4];
    __shared__ float sc;

    float m = -1e30f, s = 0.f;
    for (int i = tid; i < VOCABN / 4; i += 256) {
        float4 v = p4[i];
        float cm = fmaxf(fmaxf(v.x, v.y), fmaxf(v.z, v.w));
        if (cm > m) { s *= __expf(m - cm); m = cm; }
        s += __expf(v.x - m) + __expf(v.y - m) + __expf(v.z - m) + __expf(v.w - m);
    }
#pragma unroll
    for (int off = 1; off < 64; off <<= 1) {
        float om = __shfl_xor(m, off, 64);
        float os = __shfl_xor(s, off, 64);
        float nm = fmaxf(m, om);
        s = s * __expf(m - nm) + os * __expf(om - nm);
        m = nm;
    }
    if (lane == 0) sred[w] = make_float2(m, s);
    __syncthreads();
    if (tid == 0) {
        float fm = sred[0].x, fs = sred[0].y;
#pragma unroll
        for (int k = 1; k < 4; ++k) {
            float om = sred[k].x, os = sred[k].y;
            float nm = fmaxf(fm, om);
            fs = fs * __expf(fm - nm) + os * __expf(om - nm);
            fm = nm;
        }
        sc = fm + logf(fs);
    }
    __syncthreads();
    float c = sc;
    for (int i = tid; i < VOCABN / 4; i += 256) {
        float4 v = p4[i];
        v.x -= c; v.y -= c; v.z -= c; v.w -= c;
        p4[i] = v;
    }
}

// ----------------------------------------------------------------
extern "C" void kernel_launch(void* const* d_in, const int* in_sizes, int n_in,
                              void* d_out, int out_size, void* d_ws, size_t ws_size,
                              hipStream_t stream) {
    const float* enc_h  = (const float*)d_in[1];
    const int*   target = (const int*)d_in[2];
    const float* emb    = (const float*)d_in[3];
    const float* w_ih   = (const float*)d_in[4];
    const float* w_hh   = (const float*)d_in[5];
    const float* b_ih   = (const float*)d_in[6];
    const float* b_hh   = (const float*)d_in[7];
    const float* out_w  = (const float*)d_in[8];
    const float* out_b  = (const float*)d_in[9];
    float* out = (float*)d_out;

    char* p0 = (char*)d_ws;
    char* p = p0;
    unsigned short* Xb   = (unsigned short*)p; p += (size_t)ROWS * HID * 2;
    unsigned short* Wih  = (unsigned short*)p; p += (size_t)G3 * HID * 2;
    unsigned short* OutW = (unsigned short*)p; p += (size_t)VOCABN * HID * 2;
    unsigned short* Hall = (unsigned short*)p; p += (size_t)ROWS_PAD * HID * 2;
    float* gi   = (float*)p; p += (size_t)ROWS * G3 * 4;
    unsigned short* Whhb = (unsigned short*)p; p += (size_t)G3 * HID * 2;
    unsigned short* h0b  = (unsigned short*)p; p += (size_t)BATCH * HID * 2;
    unsigned int* bar = (unsigned int*)p; p += 256 * sizeof(unsigned int);
    unsigned short* lscratch = (unsigned short*)p; p += (size_t)ROWS * VOCABN * 2;  // 122.88 MB
    const bool use_bf16 = ((size_t)(p - p0) <= ws_size);
    unsigned int* ctr = bar + 64;   // [0]=work counter, [1]=convdone

    f32_to_bf16<<<768, 256, 0, stream>>>(w_ih, Wih, G3 * HID / 4);
    f32_to_bf16<<<768, 256, 0, stream>>>(w_hh, Whhb, G3 * HID / 4);
    f32_to_bf16<<<64, 256, 0, stream>>>(enc_h, h0b, BATCH * HID / 4);
    embed_relu_bf16<<<ROWS, 256, 0, stream>>>(target, emb, Xb);
    init_bar<<<1, 128, 0, stream>>>(bar);

    gemm_mfma_bt<<<dim3(G3 / 128, ROWS / 128), 256, 0, stream>>>(Xb, Wih, b_ih, gi, G3, HID);

    {
        const unsigned short* a0 = h0b;
        const float* a1 = enc_h;
        const unsigned short* a2 = Whhb;
        const float* a3 = b_hh;
        const float* a4 = gi;
        unsigned short* a5 = Hall;
        float* a6 = out + OUT_HID_OFF;
        unsigned int* a7 = bar;
        unsigned int* a8 = ctr;
        const float* a9 = out_w;
        unsigned short* a10 = OutW;
        const float* a11 = out_b;
        float* a12 = out;
        unsigned short* a13 = lscratch;
        void* args[] = {&a0, &a1, &a2, &a3, &a4, &a5, &a6, &a7, &a8,
                        &a9, &a10, &a11, &a12, &a13};
        if (use_bf16)
            hipLaunchCooperativeKernel((void*)fused_coop<true>, dim3(256), dim3(512),
                                       args, 0, stream);
        else
            hipLaunchCooperativeKernel((void*)fused_coop<false>, dim3(256), dim3(512),
                                       args, 0, stream);
    }

    if (use_bf16) lsm_fused_bf16<<<ROWS, 256, 0, stream>>>(lscratch, out);
    else          lsm_fused<<<ROWS, 256, 0, stream>>>(out);
}